// Round 13
// baseline (208.483 us; speedup 1.0000x reference)
//
#include <hip/hip_runtime.h>
#include <math.h>

constexpr int T_ = 1024;
constexpr int C_ = 1024;
constexpr int H_ = 16;
constexpr int D_ = 64;
#define SCALE 0.125f

typedef unsigned short u16;
typedef __attribute__((ext_vector_type(8))) short short8;
typedef __attribute__((ext_vector_type(4))) float f32x4;

__device__ __forceinline__ float elu1(float x) { return x > 0.f ? x + 1.f : expf(x); }

__device__ __forceinline__ u16 f2bf(float f) {
    union { float f; unsigned u; } c; c.f = f;
    unsigned r = (c.u + 0x7fffu + ((c.u >> 16) & 1u)) >> 16;
    return (u16)r;
}
__device__ __forceinline__ float bf2f(u16 u) {
    union { unsigned u; float f; } c; c.u = (unsigned)u << 16;
    return c.f;
}

#define GLL16(g, l)                                                            \
    __builtin_amdgcn_global_load_lds(                                          \
        (const __attribute__((address_space(1))) void*)(g),                    \
        (__attribute__((address_space(3))) void*)(l), 16, 0, 0)

// ---------------------------------------------------------------------------
// K0_prep: fused x-cast (blocks [0,2048)), W-cast ([2048,5120)), and
// Mg = alpha * wcol @ wrow^T (block 5120).
// ---------------------------------------------------------------------------
__global__ __launch_bounds__(256) void k0_prep(
    const float* __restrict__ x, const float* __restrict__ w,
    const float* __restrict__ wcol, const float* __restrict__ wrow,
    const float* __restrict__ palpha,
    u16* __restrict__ xbf, u16* __restrict__ wbf, float* __restrict__ Mg)
{
    const int b = blockIdx.x;
    const int tid = threadIdx.x;
    if (b < 2048) {
        int i = b * 256 + tid;
        float4 v = reinterpret_cast<const float4*>(x)[i];
        ushort4 o;
        o.x = f2bf(v.x); o.y = f2bf(v.y); o.z = f2bf(v.z); o.w = f2bf(v.w);
        reinterpret_cast<ushort4*>(xbf)[i] = o;
    } else if (b < 5120) {
        int i = (b - 2048) * 256 + tid;
        float4 v = reinterpret_cast<const float4*>(w)[i];
        ushort4 o;
        o.x = f2bf(v.x); o.y = f2bf(v.y); o.z = f2bf(v.z); o.w = f2bf(v.w);
        reinterpret_cast<ushort4*>(wbf)[i] = o;
    } else {
        const int j = tid >> 3, r0 = (tid & 7) << 2;
        const float al = palpha[0];
        float acc[4] = {0.f, 0.f, 0.f, 0.f};
        for (int c = 0; c < 32; c++) {
            float wc = wcol[(j << 5) + c];
#pragma unroll
            for (int q = 0; q < 4; q++) acc[q] += wc * wrow[((r0 + q) << 5) + c];
        }
        float4 o = {al * acc[0], al * acc[1], al * acc[2], al * acc[3]};
        *reinterpret_cast<float4*>(&Mg[(j << 5) + r0]) = o;
    }
}

// ---------------------------------------------------------------------------
// K1: bf16 MFMA GEMM  qkv = x @ W^T + b  (M=2048,N=3072,K=1024).
// (R11 GLL16 staging — reg-prefetch variant measured neutral, reverted.)
// v-blocks also emit the transposed copy vtb[bh][d][t] (packed uint2).
// ---------------------------------------------------------------------------
__global__ __launch_bounds__(256) void k1_qkv(
    const u16* __restrict__ xbf, const u16* __restrict__ wbf,
    const float* __restrict__ bias,
    u16* __restrict__ qb, u16* __restrict__ kb, u16* __restrict__ vb,
    u16* __restrict__ vtb)
{
    __shared__ __align__(16) u16 As[128 * 32];
    __shared__ __align__(16) u16 Bs[128 * 32];
    const int tid = threadIdx.x;
    const int wave = tid >> 6, lane = tid & 63;
    const int quad = lane >> 4, l15 = lane & 15;
    const int m0 = blockIdx.y << 7, n0 = blockIdx.x << 7;
    const int wm = (wave >> 1) << 6, wn = (wave & 1) << 6;

    const int rowS = (wave << 5) + (lane >> 2);
    const int seg8 = (lane & 3) << 3;
    const u16* gA1 = xbf + (size_t)(m0 + rowS) * 1024 + seg8;
    const u16* gA2 = gA1 + (size_t)16 * 1024;
    const u16* gB1 = wbf + (size_t)(n0 + rowS) * 1024 + seg8;
    const u16* gB2 = gB1 + (size_t)16 * 1024;
    u16* lA1 = &As[(wave << 5) * 32];
    u16* lA2 = lA1 + 16 * 32;
    u16* lB1 = &Bs[(wave << 5) * 32];
    u16* lB2 = lB1 + 16 * 32;

    f32x4 zero4 = {0.f, 0.f, 0.f, 0.f};
    f32x4 acc[4][4];
#pragma unroll
    for (int i = 0; i < 4; i++)
#pragma unroll
        for (int j = 0; j < 4; j++) acc[i][j] = zero4;

    for (int k0 = 0; k0 < 1024; k0 += 32) {
        GLL16(gA1 + k0, lA1);
        GLL16(gA2 + k0, lA2);
        GLL16(gB1 + k0, lB1);
        GLL16(gB2 + k0, lB2);
        __syncthreads();
        short8 a[4], b[4];
#pragma unroll
        for (int mi = 0; mi < 4; mi++)
            a[mi] = *(const short8*)&As[(wm + mi * 16 + l15) * 32 + (quad << 3)];
#pragma unroll
        for (int ni = 0; ni < 4; ni++)
            b[ni] = *(const short8*)&Bs[(wn + ni * 16 + l15) * 32 + (quad << 3)];
#pragma unroll
        for (int mi = 0; mi < 4; mi++)
#pragma unroll
            for (int ni = 0; ni < 4; ni++)
                acc[mi][ni] = __builtin_amdgcn_mfma_f32_16x16x32_bf16(
                    a[mi], b[ni], acc[mi][ni], 0, 0, 0);
        __syncthreads();
    }
#pragma unroll
    for (int ni = 0; ni < 4; ni++) {
        int n_g = n0 + wn + ni * 16 + l15;
        int which = n_g >> 10;
        int h = (n_g >> 6) & 15;
        int d = n_g & 63;
        u16* dst = (which == 0) ? qb : (which == 1) ? kb : vb;
        float bz = bias[n_g];
#pragma unroll
        for (int mi = 0; mi < 4; mi++) {
            int m_base = m0 + wm + mi * 16 + (quad << 2);
            int bi = m_base >> 10, t_base = m_base & 1023;
            u16 o4[4];
#pragma unroll
            for (int reg = 0; reg < 4; reg++) {
                o4[reg] = f2bf(acc[mi][ni][reg] + bz);
                dst[((size_t)(bi * 16 + h) << 16) + ((size_t)(t_base + reg) << 6)
                    + d] = o4[reg];
            }
            if (which == 2) {
                *(uint2*)&vtb[(((size_t)((bi * 16 + h) << 6) + d) << 10) +
                              t_base] = *(uint2*)o4;
            }
        }
    }
}

// ---------------------------------------------------------------------------
// K23: merged k2a (chunk KV states, fp32 VALU) + k3a (split-K flash partials,
// cooperative LDS staging with one-tile register prefetch).  Pa rows are
// wave-private (no barrier needed).
// blockIdx.x < 32: k3a job = 31 - blockIdx.x; else k2a chunk = x - 32.
// ---------------------------------------------------------------------------
__global__ __launch_bounds__(256) void k23(
    const u16* __restrict__ qbp, const u16* __restrict__ kbp,
    const u16* __restrict__ vbp, const u16* __restrict__ vtb,
    float* __restrict__ Sg, float* __restrict__ svg,
    float* __restrict__ Op, float* __restrict__ ml)
{
    __shared__ __align__(16) u16 smem[4 * 64 * 72];  // 36864 B union
    const int bh = blockIdx.y;
    const int tid = threadIdx.x;

    if (blockIdx.x < 32) {
        // ----- k3a: flash attention partial, reg-prefetch pipeline -----
        const int job = 31 - (int)blockIdx.x;
        const int qi = job >> 1, half = job & 1;
        const int n = qi + 1;
        const int csplit = n >> 1;
        const int kbeg = half ? csplit : 0;
        const int kend = half ? n : csplit;
        u16 (*Qs)[72] = (u16(*)[72])smem;
        u16 (*Ks)[72] = (u16(*)[72])(smem + 4608);
        u16 (*Vt)[72] = (u16(*)[72])(smem + 9216);
        u16 (*Pa)[72] = (u16(*)[72])(smem + 13824);
        const int wave = tid >> 6, lane = tid & 63;
        const int quad = lane >> 4, l15 = lane & 15;
        const f32x4 zero4 = {0.f, 0.f, 0.f, 0.f};
        const int sidx0 = tid << 3;
        const int sidx1 = (tid + 256) << 3;
        const int sr0 = sidx0 >> 6, sc0 = sidx0 & 63;
        const int sr1 = sidx1 >> 6, sc1 = sidx1 & 63;

        *(uint4*)&Qs[sr0][sc0] = *(const uint4*)
            &qbp[((size_t)bh << 16) + ((size_t)((qi << 6) + sr0) << 6) + sc0];
        *(uint4*)&Qs[sr1][sc1] = *(const uint4*)
            &qbp[((size_t)bh << 16) + ((size_t)((qi << 6) + sr1) << 6) + sc1];
        __syncthreads();
        short8 bq[2];
        bq[0] = *(const short8*)&Qs[(wave << 4) + l15][(quad << 3)];
        bq[1] = *(const short8*)&Qs[(wave << 4) + l15][32 + (quad << 3)];
        f32x4 O[4];
#pragma unroll
        for (int dt = 0; dt < 4; dt++) O[dt] = zero4;
        float m_run = -INFINITY, l_run = 0.f;
        const int r_g = (qi << 6) + (wave << 4) + l15;

        uint4 kreg0, kreg1, vreg0, vreg1;
        {
            const int ki = kbeg;
            kreg0 = *(const uint4*)
                &kbp[((size_t)bh << 16) + ((size_t)((ki << 6) + sr0) << 6) + sc0];
            kreg1 = *(const uint4*)
                &kbp[((size_t)bh << 16) + ((size_t)((ki << 6) + sr1) << 6) + sc1];
            vreg0 = *(const uint4*)
                &vtb[(((size_t)(bh << 6) + sr0) << 10) + (ki << 6) + sc0];
            vreg1 = *(const uint4*)
                &vtb[(((size_t)(bh << 6) + sr1) << 10) + (ki << 6) + sc1];
        }

        for (int ki = kbeg; ki < kend; ki++) {
            __syncthreads();
            *(uint4*)&Ks[sr0][sc0] = kreg0;
            *(uint4*)&Ks[sr1][sc1] = kreg1;
            *(uint4*)&Vt[sr0][sc0] = vreg0;
            *(uint4*)&Vt[sr1][sc1] = vreg1;
            __syncthreads();
            if (ki + 1 < kend) {
                const int kn = ki + 1;
                kreg0 = *(const uint4*)
                    &kbp[((size_t)bh << 16) + ((size_t)((kn << 6) + sr0) << 6) + sc0];
                kreg1 = *(const uint4*)
                    &kbp[((size_t)bh << 16) + ((size_t)((kn << 6) + sr1) << 6) + sc1];
                vreg0 = *(const uint4*)
                    &vtb[(((size_t)(bh << 6) + sr0) << 10) + (kn << 6) + sc0];
                vreg1 = *(const uint4*)
                    &vtb[(((size_t)(bh << 6) + sr1) << 10) + (kn << 6) + sc1];
            }
            f32x4 st[4];
#pragma unroll
            for (int ct = 0; ct < 4; ct++) st[ct] = zero4;
#pragma unroll
            for (int ks = 0; ks < 2; ks++) {
#pragma unroll
                for (int ct = 0; ct < 4; ct++) {
                    short8 a = *(const short8*)
                        &Ks[(ct << 4) + l15][(ks << 5) + (quad << 3)];
                    st[ct] = __builtin_amdgcn_mfma_f32_16x16x32_bf16(
                        a, bq[ks], st[ct], 0, 0, 0);
                }
            }
            float mloc = -INFINITY;
#pragma unroll
            for (int ct = 0; ct < 4; ct++)
#pragma unroll
                for (int reg = 0; reg < 4; reg++) {
                    int c_g = (ki << 6) + (ct << 4) + (quad << 2) + reg;
                    float s = st[ct][reg] * SCALE;
                    if (c_g > r_g) s = -INFINITY;
                    st[ct][reg] = s;
                    mloc = fmaxf(mloc, s);
                }
            mloc = fmaxf(mloc, __shfl_xor(mloc, 16));
            mloc = fmaxf(mloc, __shfl_xor(mloc, 32));
            float mnew = fmaxf(m_run, mloc);
            float corr = __expf(m_run - mnew);
            m_run = mnew;
            float rsum = 0.f;
#pragma unroll
            for (int ct = 0; ct < 4; ct++) {
                u16 pk[4];
#pragma unroll
                for (int reg = 0; reg < 4; reg++) {
                    float pv = __expf(st[ct][reg] - mnew);
                    rsum += pv;
                    pk[reg] = f2bf(pv);
                }
                uint2 pkv;
                pkv.x = (unsigned)pk[0] | ((unsigned)pk[1] << 16);
                pkv.y = (unsigned)pk[2] | ((unsigned)pk[3] << 16);
                *(uint2*)&Pa[(wave << 4) + l15][(ct << 4) + (quad << 2)] = pkv;
            }
            rsum += __shfl_xor(rsum, 16);
            rsum += __shfl_xor(rsum, 32);
            l_run = l_run * corr + rsum;
            float co[4];
#pragma unroll
            for (int reg = 0; reg < 4; reg++)
                co[reg] = __shfl(corr, ((lane >> 4) << 2) + reg);
#pragma unroll
            for (int dt = 0; dt < 4; dt++)
#pragma unroll
                for (int reg = 0; reg < 4; reg++) O[dt][reg] *= co[reg];
            __builtin_amdgcn_wave_barrier();
#pragma unroll
            for (int ks = 0; ks < 2; ks++) {
                short8 ap = *(const short8*)
                    &Pa[(wave << 4) + l15][(ks << 5) + (quad << 3)];
#pragma unroll
                for (int dt = 0; dt < 4; dt++) {
                    short8 bv = *(const short8*)
                        &Vt[(dt << 4) + l15][(ks << 5) + (quad << 3)];
                    O[dt] = __builtin_amdgcn_mfma_f32_16x16x32_bf16(
                        ap, bv, O[dt], 0, 0, 0);
                }
            }
        }
        float* ob = Op + (((size_t)bh * 32 + job) << 12);
#pragma unroll
        for (int dt = 0; dt < 4; dt++)
#pragma unroll
            for (int reg = 0; reg < 4; reg++) {
                int r = (wave << 4) + (quad << 2) + reg;
                int d = (dt << 4) + l15;
                ob[(r << 6) + d] = O[dt][reg];
            }
        if (quad == 0) {
            int r = (wave << 4) + l15;
            float* mlb = ml + (((size_t)bh * 32 + job) << 7);
            mlb[r] = m_run;
            mlb[64 + r] = l_run;
        }
    } else {
        // ----- k2a: chunk KV state (fp32 VALU, unchanged numerics) -----
        const int chunk = (int)blockIdx.x - 32;
        const int t0 = chunk << 6;
        float* Ksf = (float*)smem;            // [64][65]
        float* Vsf = Ksf + 64 * 65;           // [64][65]
        const u16* kp = kbp + (size_t)bh * T_ * D_;
        const u16* vp = vbp + (size_t)bh * T_ * D_;
#pragma unroll
        for (int ii = 0; ii < 16; ii++) {
            int idx = tid + (ii << 8);
            int row = idx >> 6, col = idx & 63;
            Ksf[row * 65 + col] =
                elu1(bf2f(kp[(size_t)(t0 + row) * D_ + col]) * SCALE);
            Vsf[row * 65 + col] = bf2f(vp[(size_t)(t0 + row) * D_ + col]);
        }
        __syncthreads();
        const int tr = tid >> 4, tc = tid & 15;
        const int d0 = tr * 4, e0 = tc * 4;
        float acc[4][4] = {};
        for (int c = 0; c < 64; c++) {
            float a[4], b[4];
#pragma unroll
            for (int i = 0; i < 4; i++) a[i] = Ksf[c * 65 + d0 + i];
#pragma unroll
            for (int j = 0; j < 4; j++) b[j] = Vsf[c * 65 + e0 + j];
#pragma unroll
            for (int i = 0; i < 4; i++)
#pragma unroll
                for (int j = 0; j < 4; j++) acc[i][j] += a[i] * b[j];
        }
        float* so = Sg + ((size_t)bh * 16 + chunk) * 4096;
#pragma unroll
        for (int i = 0; i < 4; i++) {
            float4 o = {acc[i][0], acc[i][1], acc[i][2], acc[i][3]};
            *reinterpret_cast<float4*>(&so[(d0 + i) * 64 + e0]) = o;
        }
        if (tc == 0) {
#pragma unroll
            for (int i = 0; i < 4; i++) {
                float s = 0.f;
                for (int c = 0; c < 64; c++) s += Ksf[c * 65 + d0 + i];
                svg[((size_t)bh * 16 + chunk) * 64 + d0 + i] = s;
            }
        }
    }
}

// ---------------------------------------------------------------------------
// K2b: linear attention per chunk (fp32 VALU).  Exclusive-prefix state is
// accumulated in-kernel from the raw chunk states (k2s launch deleted);
// summation order matches the old scan (c ascending) -> bit-identical.
// ---------------------------------------------------------------------------
__global__ __launch_bounds__(256) void k2b_lin(
    const u16* __restrict__ qbp, const u16* __restrict__ kbp,
    const u16* __restrict__ vbp,
    const float* __restrict__ Sg, const float* __restrict__ svg,
    const float* __restrict__ ang, const float* __restrict__ anb,
    float* __restrict__ ylin)
{
    const int chunk = blockIdx.x, bh = blockIdx.y;
    const int t0 = chunk << 6;
    __shared__ __align__(16) float bufA[64][68];
    __shared__ float bufQ[64][65];
    __shared__ float bufK[64][65];
    __shared__ float svec[64];
    const int tid = threadIdx.x;
    const u16* qp = qbp + (size_t)bh * T_ * D_;
    const u16* kp = kbp + (size_t)bh * T_ * D_;
    const u16* vp = vbp + (size_t)bh * T_ * D_;
    // exclusive prefix over raw chunk states (coalesced float4, L2-resident)
    const float* sgb = Sg + ((size_t)bh << 16);
#pragma unroll
    for (int u = 0; u < 4; u++) {
        int idx = (tid + (u << 8)) << 2;
        float4 a4 = {0.f, 0.f, 0.f, 0.f};
        for (int c = 0; c < chunk; c++) {
            float4 v = *(const float4*)&sgb[((size_t)c << 12) + idx];
            a4.x += v.x; a4.y += v.y; a4.z += v.z; a4.w += v.w;
        }
        int dd = idx >> 6, e = idx & 63;
        *(float4*)&bufA[dd][e] = a4;
    }
    if (tid < 64) {
        float s = 0.f;
        const float* svb = svg + ((size_t)bh << 10);
        for (int c = 0; c < chunk; c++) s += svb[(c << 6) + tid];
        svec[tid] = s;
    }
#pragma unroll
    for (int ii = 0; ii < 16; ii++) {
        int idx = tid + (ii << 8);
        int row = idx >> 6, col = idx & 63;
        bufQ[col][row] = elu1(bf2f(qp[(size_t)(t0 + row) * D_ + col]) * SCALE);
    }
    __syncthreads();
    const int tr = tid >> 4, tc = tid & 15;
    const int r0 = tr * 4, c0 = tc * 4;
    float N[4][4] = {};
    float pden[4];
    for (int dd = 0; dd < 64; dd++) {
        float a[4], b[4];
#pragma unroll
        for (int i = 0; i < 4; i++) a[i] = bufQ[dd][r0 + i];
#pragma unroll
        for (int j = 0; j < 4; j++) b[j] = bufA[dd][c0 + j];
#pragma unroll
        for (int i = 0; i < 4; i++)
#pragma unroll
            for (int j = 0; j < 4; j++) N[i][j] += a[i] * b[j];
    }
#pragma unroll
    for (int i = 0; i < 4; i++) {
        float s = 0.f;
#pragma unroll
        for (int j = 0; j < 4; j++) s += bufQ[c0 + j][r0 + i] * svec[c0 + j];
        pden[i] = s;
    }
    __syncthreads();
#pragma unroll
    for (int ii = 0; ii < 16; ii++) {
        int idx = tid + (ii << 8);
        int row = idx >> 6, col = idx & 63;
        bufK[col][row] = elu1(bf2f(kp[(size_t)(t0 + row) * D_ + col]) * SCALE);
        bufA[row][col] = bf2f(vp[(size_t)(t0 + row) * D_ + col]);
    }
    __syncthreads();
    float sc[4][4] = {};
    for (int dd = 0; dd < 64; dd++) {
        float a[4], b[4];
#pragma unroll
        for (int i = 0; i < 4; i++) a[i] = bufQ[dd][r0 + i];
#pragma unroll
        for (int j = 0; j < 4; j++) b[j] = bufK[dd][c0 + j];
#pragma unroll
        for (int i = 0; i < 4; i++)
#pragma unroll
            for (int j = 0; j < 4; j++) sc[i][j] += a[i] * b[j];
    }
    __syncthreads();
#pragma unroll
    for (int i = 0; i < 4; i++) {
        float s = 0.f;
#pragma unroll
        for (int j = 0; j < 4; j++) {
            float pv = ((c0 + j) <= (r0 + i)) ? sc[i][j] : 0.f;
            bufQ[c0 + j][r0 + i] = pv;
            s += pv;
        }
        pden[i] += s;
    }
#pragma unroll
    for (int i = 0; i < 4; i++) {
#pragma unroll
        for (int off = 1; off < 16; off <<= 1)
            pden[i] += __shfl_xor(pden[i], off);
    }
    __syncthreads();
    for (int c = 0; c < 64; c++) {
        float a[4], b[4];
#pragma unroll
        for (int i = 0; i < 4; i++) a[i] = bufQ[c][r0 + i];
#pragma unroll
        for (int j = 0; j < 4; j++) b[j] = bufA[c][c0 + j];
#pragma unroll
        for (int i = 0; i < 4; i++)
#pragma unroll
            for (int j = 0; j < 4; j++) N[i][j] += a[i] * b[j];
    }
    float yv[4][4], s1[4], s2[4];
#pragma unroll
    for (int i = 0; i < 4; i++) {
        float inv = 1.f / (pden[i] + 1e-4f);
        s1[i] = 0.f; s2[i] = 0.f;
#pragma unroll
        for (int j = 0; j < 4; j++) {
            float t = N[i][j] * inv;
            yv[i][j] = t; s1[i] += t; s2[i] += t * t;
        }
    }
#pragma unroll
    for (int i = 0; i < 4; i++) {
#pragma unroll
        for (int off = 1; off < 16; off <<= 1) {
            s1[i] += __shfl_xor(s1[i], off);
            s2[i] += __shfl_xor(s2[i], off);
        }
    }
#pragma unroll
    for (int i = 0; i < 4; i++) {
        float mean = s1[i] * (1.f / 64.f);
        float var = s2[i] * (1.f / 64.f) - mean * mean;
        float rstd = rsqrtf(var + 1e-5f);
        float4 o;
        o.x = (yv[i][0] - mean) * rstd * ang[c0 + 0] + anb[c0 + 0];
        o.y = (yv[i][1] - mean) * rstd * ang[c0 + 1] + anb[c0 + 1];
        o.z = (yv[i][2] - mean) * rstd * ang[c0 + 2] + anb[c0 + 2];
        o.w = (yv[i][3] - mean) * rstd * ang[c0 + 3] + anb[c0 + 3];
        *reinterpret_cast<float4*>(
            &ylin[((size_t)bh * T_ + t0 + r0 + i) * D_ + c0]) = o;
    }
}

// ---------------------------------------------------------------------------
// K4: fused split-K combine + alpha-blend + out-LN + pre-LN + block-diag mix
// (reversed) + folded bilinear + bias.  One block per token.
// ---------------------------------------------------------------------------
__global__ __launch_bounds__(256) void k4_proj(
    const float* __restrict__ Op, const float* __restrict__ ml,
    const float* __restrict__ ylin, const float* __restrict__ fg,
    const float* __restrict__ og, const float* __restrict__ ob,
    const float* __restrict__ pg, const float* __restrict__ pb,
    const float* __restrict__ bw, const float* __restrict__ Mg,
    const float* __restrict__ pbias, float* __restrict__ out)
{
    const int tok = blockIdx.x;
    const int bi = tok >> 10, t = tok & 1023;
    const int qi = t >> 6, r = t & 63;
    __shared__ float ybuf[1024];
    __shared__ float xb[1024];
    __shared__ float red[8];
    const int tid = threadIdx.x;
    {
        const float al = 1.f / (1.f + __expf(-fg[0]));
        const int h = tid >> 4;
        const int d4 = (tid & 15) << 2;
        const int bh = (bi << 4) + h;
        const size_t b0 = (((size_t)bh * 32 + (qi << 1)) << 7);
        float m0 = ml[b0 + r], l0 = ml[b0 + 64 + r];
        float m1 = ml[b0 + 128 + r], l1 = ml[b0 + 192 + r];
        float m = fmaxf(m0, m1);
        float w0 = (m0 == -INFINITY) ? 0.f : __expf(m0 - m);
        float w1 = __expf(m1 - m);
        float inv = al / (l0 * w0 + l1 * w1);
        const float* o0 = Op + (((size_t)bh * 32 + (qi << 1)) << 12) + (r << 6);
        const float* o1 = o0 + 4096;
        float4 a = *(const float4*)&o0[d4];
        float4 b = *(const float4*)&o1[d4];
        float4 yl = *(const float4*)
            &ylin[((((size_t)bh << 10) + t) << 6) + d4];
        float4 o;
        o.x = (a.x * w0 + b.x * w1) * inv + (1.f - al) * yl.x;
        o.y = (a.y * w0 + b.y * w1) * inv + (1.f - al) * yl.y;
        o.z = (a.z * w0 + b.z * w1) * inv + (1.f - al) * yl.z;
        o.w = (a.w * w0 + b.w * w1) * inv + (1.f - al) * yl.w;
        *(float4*)&ybuf[(h << 6) + d4] = o;
    }
    __syncthreads();
    const int c0 = tid << 2;
    float4 v4 = *reinterpret_cast<const float4*>(&ybuf[c0]);
    float v[4] = {v4.x, v4.y, v4.z, v4.w};
    float s1 = v[0] + v[1] + v[2] + v[3];
    float s2 = v[0]*v[0] + v[1]*v[1] + v[2]*v[2] + v[3]*v[3];
#pragma unroll
    for (int off = 1; off < 64; off <<= 1) {
        s1 += __shfl_xor(s1, off); s2 += __shfl_xor(s2, off);
    }
    if ((tid & 63) == 0) { red[(tid >> 6) * 2] = s1; red[(tid >> 6) * 2 + 1] = s2; }
    __syncthreads();
    s1 = red[0] + red[2] + red[4] + red[6];
    s2 = red[1] + red[3] + red[5] + red[7];
    __syncthreads();
    {
        float mean = s1 * (1.f / 1024.f);
        float var = s2 * (1.f / 1024.f) - mean * mean;
        float rstd = rsqrtf(var + 1e-5f);
#pragma unroll
        for (int q = 0; q < 4; q++)
            v[q] = (v[q] - mean) * rstd * og[c0 + q] + ob[c0 + q];
    }
    s1 = v[0] + v[1] + v[2] + v[3];
    s2 = v[0]*v[0] + v[1]*v[1] + v[2]*v[2] + v[3]*v[3];
#pragma unroll
    for (int off = 1; off < 64; off <<= 1) {
        s1 += __shfl_xor(s1, off); s2 += __shfl_xor(s2, off);
    }
    if ((tid & 63) == 0) { red[(tid >> 6) * 2] = s1; red[(tid >> 6) * 2 + 1] = s2; }
    __syncthreads();
    s1 = red[0] + red[2] + red[4] + red[6];
    s2 = red[1] + red[3] + red[5] + red[7];
    {
        float mean = s1 * (1.f / 1024.f);
        float var = s2 * (1.f / 1024.f) - mean * mean;
        float rstd = rsqrtf(var + 1e-5f);
#pragma unroll
        for (int q = 0; q < 4; q++)
            xb[c0 + q] = (v[q] - mean) * rstd * pg[c0 + q] + pb[c0 + q];
    }
    __syncthreads();
    const int g = tid >> 2;
    const int jb = (tid & 3) << 2;
    float acc[4] = {0.f, 0.f, 0.f, 0.f};
    {
        const float* xg = &xb[g << 4];
        const float* bwg = &bw[(g << 8) + jb];
        for (int i = 0; i < 16; i++) {
            float xv = xg[i];
            float4 wv = *reinterpret_cast<const float4*>(&bwg[i << 4]);
            acc[0] += xv * wv.x; acc[1] += xv * wv.y;
            acc[2] += xv * wv.z; acc[3] += xv * wv.w;
        }
    }
    const int C0 = ((63 - g) << 4) + 12 - jb;
    const int i2 = C0 >> 5, r0 = C0 & 31;
    float z2[4] = {0.f, 0.f, 0.f, 0.f};
    {
        const float* xg = &xb[i2 << 5];
        const float* mg = &Mg[r0];
        for (int j = 0; j < 32; j++) {
            float xv = xg[j];
            float4 mv = *reinterpret_cast<const float4*>(&mg[j << 5]);
            z2[0] += xv * mv.x; z2[1] += xv * mv.y;
            z2[2] += xv * mv.z; z2[3] += xv * mv.w;
        }
    }
    float4 bz = *reinterpret_cast<const float4*>(&pbias[C0]);
    float4 o;
    o.x = acc[3] + z2[0] + bz.x;
    o.y = acc[2] + z2[1] + bz.y;
    o.z = acc[1] + z2[2] + bz.z;
    o.w = acc[0] + z2[3] + bz.w;
    *reinterpret_cast<float4*>(&out[((size_t)tok << 10) + C0]) = o;
}

// ---------------------------------------------------------------------------
extern "C" void kernel_launch(void* const* d_in, const int* in_sizes, int n_in,
                              void* d_out, int out_size, void* d_ws, size_t ws_size,
                              hipStream_t stream) {
    const float* x   = (const float*)d_in[0];
    const float* w   = (const float*)d_in[1];
    const float* wb  = (const float*)d_in[2];
    const float* fg  = (const float*)d_in[3];
    const float* ang = (const float*)d_in[4];
    const float* anb = (const float*)d_in[5];
    const float* ong = (const float*)d_in[6];
    const float* onb = (const float*)d_in[7];
    const float* ppg = (const float*)d_in[8];
    const float* ppb = (const float*)d_in[9];
    const float* pbw = (const float*)d_in[10];
    const float* pwr = (const float*)d_in[11];
    const float* pwc = (const float*)d_in[12];
    const float* pal = (const float*)d_in[13];
    const float* pbi = (const float*)d_in[14];

    uint8_t* p = (uint8_t*)d_ws;
    u16* xbf = (u16*)p;  p += (size_t)2048 * 1024 * 2;
    u16* wbf = (u16*)p;  p += (size_t)3072 * 1024 * 2;
    u16* qb  = (u16*)p;  p += (size_t)32 * 1024 * 64 * 2;
    u16* kb  = (u16*)p;  p += (size_t)32 * 1024 * 64 * 2;
    u16* vb  = (u16*)p;  p += (size_t)32 * 1024 * 64 * 2;
    u16* vtb = (u16*)p;  p += (size_t)32 * 1024 * 64 * 2;
    float* ylin  = (float*)p;  p += (size_t)32 * 1024 * 64 * 4;
    float* Sg    = (float*)p;  p += (size_t)32 * 16 * 4096 * 4;
    float* svg   = (float*)p;  p += (size_t)32 * 16 * 64 * 4;
    float* Mg    = (float*)p;  p += (size_t)32 * 32 * 4;
    float* Op    = (float*)p;  p += (size_t)32 * 32 * 4096 * 4;
    float* ml    = (float*)p;  p += (size_t)32 * 32 * 128 * 4;
    float* out   = (float*)d_out;

    k0_prep<<<5121, 256, 0, stream>>>(x, w, pwc, pwr, pal, xbf, wbf, Mg);
    k1_qkv<<<dim3(24, 16), 256, 0, stream>>>(xbf, wbf, wb, qb, kb, vb, vtb);
    k23<<<dim3(48, 32), 256, 0, stream>>>(qb, kb, vb, vtb, Sg, svg, Op, ml);
    k2b_lin<<<dim3(16, 32), 256, 0, stream>>>(qb, kb, vb, Sg, svg, ang, anb, ylin);
    k4_proj<<<2048, 256, 0, stream>>>(Op, ml, ylin, fg, ong, onb, ppg, ppb,
                                      pbw, Mg, pbi, out);
}

// Round 14
// 198.429 us; speedup vs baseline: 1.0507x; 1.0507x over previous
//
#include <hip/hip_runtime.h>
#include <math.h>

constexpr int T_ = 1024;
constexpr int C_ = 1024;
constexpr int H_ = 16;
constexpr int D_ = 64;
#define SCALE 0.125f

typedef unsigned short u16;
typedef __attribute__((ext_vector_type(8))) short short8;
typedef __attribute__((ext_vector_type(4))) float f32x4;

__device__ __forceinline__ float elu1(float x) { return x > 0.f ? x + 1.f : expf(x); }

__device__ __forceinline__ u16 f2bf(float f) {
    union { float f; unsigned u; } c; c.f = f;
    unsigned r = (c.u + 0x7fffu + ((c.u >> 16) & 1u)) >> 16;
    return (u16)r;
}
__device__ __forceinline__ float bf2f(u16 u) {
    union { unsigned u; float f; } c; c.u = (unsigned)u << 16;
    return c.f;
}

#define GLL16(g, l)                                                            \
    __builtin_amdgcn_global_load_lds(                                          \
        (const __attribute__((address_space(1))) void*)(g),                    \
        (__attribute__((address_space(3))) void*)(l), 16, 0, 0)

// ---------------------------------------------------------------------------
// K0_prep: fused x-cast (blocks [0,2048)), W-cast ([2048,5120)), and
// Mg = alpha * wcol @ wrow^T (block 5120).
// ---------------------------------------------------------------------------
__global__ __launch_bounds__(256) void k0_prep(
    const float* __restrict__ x, const float* __restrict__ w,
    const float* __restrict__ wcol, const float* __restrict__ wrow,
    const float* __restrict__ palpha,
    u16* __restrict__ xbf, u16* __restrict__ wbf, float* __restrict__ Mg)
{
    const int b = blockIdx.x;
    const int tid = threadIdx.x;
    if (b < 2048) {
        int i = b * 256 + tid;
        float4 v = reinterpret_cast<const float4*>(x)[i];
        ushort4 o;
        o.x = f2bf(v.x); o.y = f2bf(v.y); o.z = f2bf(v.z); o.w = f2bf(v.w);
        reinterpret_cast<ushort4*>(xbf)[i] = o;
    } else if (b < 5120) {
        int i = (b - 2048) * 256 + tid;
        float4 v = reinterpret_cast<const float4*>(w)[i];
        ushort4 o;
        o.x = f2bf(v.x); o.y = f2bf(v.y); o.z = f2bf(v.z); o.w = f2bf(v.w);
        reinterpret_cast<ushort4*>(wbf)[i] = o;
    } else {
        const int j = tid >> 3, r0 = (tid & 7) << 2;
        const float al = palpha[0];
        float acc[4] = {0.f, 0.f, 0.f, 0.f};
        for (int c = 0; c < 32; c++) {
            float wc = wcol[(j << 5) + c];
#pragma unroll
            for (int q = 0; q < 4; q++) acc[q] += wc * wrow[((r0 + q) << 5) + c];
        }
        float4 o = {al * acc[0], al * acc[1], al * acc[2], al * acc[3]};
        *reinterpret_cast<float4*>(&Mg[(j << 5) + r0]) = o;
    }
}

// ---------------------------------------------------------------------------
// K1: bf16 MFMA GEMM  qkv = x @ W^T + b  (M=2048,N=3072,K=1024).
// v-blocks also emit the transposed copy vtb[bh][d][t] (packed uint2).
// ---------------------------------------------------------------------------
__global__ __launch_bounds__(256) void k1_qkv(
    const u16* __restrict__ xbf, const u16* __restrict__ wbf,
    const float* __restrict__ bias,
    u16* __restrict__ qb, u16* __restrict__ kb, u16* __restrict__ vb,
    u16* __restrict__ vtb)
{
    __shared__ __align__(16) u16 As[128 * 32];
    __shared__ __align__(16) u16 Bs[128 * 32];
    const int tid = threadIdx.x;
    const int wave = tid >> 6, lane = tid & 63;
    const int quad = lane >> 4, l15 = lane & 15;
    const int m0 = blockIdx.y << 7, n0 = blockIdx.x << 7;
    const int wm = (wave >> 1) << 6, wn = (wave & 1) << 6;

    const int rowS = (wave << 5) + (lane >> 2);
    const int seg8 = (lane & 3) << 3;
    const u16* gA1 = xbf + (size_t)(m0 + rowS) * 1024 + seg8;
    const u16* gA2 = gA1 + (size_t)16 * 1024;
    const u16* gB1 = wbf + (size_t)(n0 + rowS) * 1024 + seg8;
    const u16* gB2 = gB1 + (size_t)16 * 1024;
    u16* lA1 = &As[(wave << 5) * 32];
    u16* lA2 = lA1 + 16 * 32;
    u16* lB1 = &Bs[(wave << 5) * 32];
    u16* lB2 = lB1 + 16 * 32;

    f32x4 zero4 = {0.f, 0.f, 0.f, 0.f};
    f32x4 acc[4][4];
#pragma unroll
    for (int i = 0; i < 4; i++)
#pragma unroll
        for (int j = 0; j < 4; j++) acc[i][j] = zero4;

    for (int k0 = 0; k0 < 1024; k0 += 32) {
        GLL16(gA1 + k0, lA1);
        GLL16(gA2 + k0, lA2);
        GLL16(gB1 + k0, lB1);
        GLL16(gB2 + k0, lB2);
        __syncthreads();
        short8 a[4], b[4];
#pragma unroll
        for (int mi = 0; mi < 4; mi++)
            a[mi] = *(const short8*)&As[(wm + mi * 16 + l15) * 32 + (quad << 3)];
#pragma unroll
        for (int ni = 0; ni < 4; ni++)
            b[ni] = *(const short8*)&Bs[(wn + ni * 16 + l15) * 32 + (quad << 3)];
#pragma unroll
        for (int mi = 0; mi < 4; mi++)
#pragma unroll
            for (int ni = 0; ni < 4; ni++)
                acc[mi][ni] = __builtin_amdgcn_mfma_f32_16x16x32_bf16(
                    a[mi], b[ni], acc[mi][ni], 0, 0, 0);
        __syncthreads();
    }
#pragma unroll
    for (int ni = 0; ni < 4; ni++) {
        int n_g = n0 + wn + ni * 16 + l15;
        int which = n_g >> 10;
        int h = (n_g >> 6) & 15;
        int d = n_g & 63;
        u16* dst = (which == 0) ? qb : (which == 1) ? kb : vb;
        float bz = bias[n_g];
#pragma unroll
        for (int mi = 0; mi < 4; mi++) {
            int m_base = m0 + wm + mi * 16 + (quad << 2);
            int bi = m_base >> 10, t_base = m_base & 1023;
            u16 o4[4];
#pragma unroll
            for (int reg = 0; reg < 4; reg++) {
                o4[reg] = f2bf(acc[mi][ni][reg] + bz);
                dst[((size_t)(bi * 16 + h) << 16) + ((size_t)(t_base + reg) << 6)
                    + d] = o4[reg];
            }
            if (which == 2) {
                *(uint2*)&vtb[(((size_t)((bi * 16 + h) << 6) + d) << 10) +
                              t_base] = *(uint2*)o4;
            }
        }
    }
}

// ---------------------------------------------------------------------------
// K23: merged k2a (chunk KV states, fp32 VALU) + k3a (split-K flash partials,
// cooperative LDS staging with one-tile register prefetch).  Pa rows are
// wave-private (no barrier needed).
// blockIdx.x < 32: k3a job = 31 - blockIdx.x; else k2a chunk = x - 32.
// ---------------------------------------------------------------------------
__global__ __launch_bounds__(256) void k23(
    const u16* __restrict__ qbp, const u16* __restrict__ kbp,
    const u16* __restrict__ vbp, const u16* __restrict__ vtb,
    float* __restrict__ Sg, float* __restrict__ svg,
    float* __restrict__ Op, float* __restrict__ ml)
{
    __shared__ __align__(16) u16 smem[4 * 64 * 72];  // 36864 B union
    const int bh = blockIdx.y;
    const int tid = threadIdx.x;

    if (blockIdx.x < 32) {
        // ----- k3a: flash attention partial, reg-prefetch pipeline -----
        const int job = 31 - (int)blockIdx.x;
        const int qi = job >> 1, half = job & 1;
        const int n = qi + 1;
        const int csplit = n >> 1;
        const int kbeg = half ? csplit : 0;
        const int kend = half ? n : csplit;
        u16 (*Qs)[72] = (u16(*)[72])smem;
        u16 (*Ks)[72] = (u16(*)[72])(smem + 4608);
        u16 (*Vt)[72] = (u16(*)[72])(smem + 9216);
        u16 (*Pa)[72] = (u16(*)[72])(smem + 13824);
        const int wave = tid >> 6, lane = tid & 63;
        const int quad = lane >> 4, l15 = lane & 15;
        const f32x4 zero4 = {0.f, 0.f, 0.f, 0.f};
        const int sidx0 = tid << 3;
        const int sidx1 = (tid + 256) << 3;
        const int sr0 = sidx0 >> 6, sc0 = sidx0 & 63;
        const int sr1 = sidx1 >> 6, sc1 = sidx1 & 63;

        *(uint4*)&Qs[sr0][sc0] = *(const uint4*)
            &qbp[((size_t)bh << 16) + ((size_t)((qi << 6) + sr0) << 6) + sc0];
        *(uint4*)&Qs[sr1][sc1] = *(const uint4*)
            &qbp[((size_t)bh << 16) + ((size_t)((qi << 6) + sr1) << 6) + sc1];
        __syncthreads();
        short8 bq[2];
        bq[0] = *(const short8*)&Qs[(wave << 4) + l15][(quad << 3)];
        bq[1] = *(const short8*)&Qs[(wave << 4) + l15][32 + (quad << 3)];
        f32x4 O[4];
#pragma unroll
        for (int dt = 0; dt < 4; dt++) O[dt] = zero4;
        float m_run = -INFINITY, l_run = 0.f;
        const int r_g = (qi << 6) + (wave << 4) + l15;

        uint4 kreg0, kreg1, vreg0, vreg1;
        {
            const int ki = kbeg;
            kreg0 = *(const uint4*)
                &kbp[((size_t)bh << 16) + ((size_t)((ki << 6) + sr0) << 6) + sc0];
            kreg1 = *(const uint4*)
                &kbp[((size_t)bh << 16) + ((size_t)((ki << 6) + sr1) << 6) + sc1];
            vreg0 = *(const uint4*)
                &vtb[(((size_t)(bh << 6) + sr0) << 10) + (ki << 6) + sc0];
            vreg1 = *(const uint4*)
                &vtb[(((size_t)(bh << 6) + sr1) << 10) + (ki << 6) + sc1];
        }

        for (int ki = kbeg; ki < kend; ki++) {
            __syncthreads();
            *(uint4*)&Ks[sr0][sc0] = kreg0;
            *(uint4*)&Ks[sr1][sc1] = kreg1;
            *(uint4*)&Vt[sr0][sc0] = vreg0;
            *(uint4*)&Vt[sr1][sc1] = vreg1;
            __syncthreads();
            if (ki + 1 < kend) {
                const int kn = ki + 1;
                kreg0 = *(const uint4*)
                    &kbp[((size_t)bh << 16) + ((size_t)((kn << 6) + sr0) << 6) + sc0];
                kreg1 = *(const uint4*)
                    &kbp[((size_t)bh << 16) + ((size_t)((kn << 6) + sr1) << 6) + sc1];
                vreg0 = *(const uint4*)
                    &vtb[(((size_t)(bh << 6) + sr0) << 10) + (kn << 6) + sc0];
                vreg1 = *(const uint4*)
                    &vtb[(((size_t)(bh << 6) + sr1) << 10) + (kn << 6) + sc1];
            }
            f32x4 st[4];
#pragma unroll
            for (int ct = 0; ct < 4; ct++) st[ct] = zero4;
#pragma unroll
            for (int ks = 0; ks < 2; ks++) {
#pragma unroll
                for (int ct = 0; ct < 4; ct++) {
                    short8 a = *(const short8*)
                        &Ks[(ct << 4) + l15][(ks << 5) + (quad << 3)];
                    st[ct] = __builtin_amdgcn_mfma_f32_16x16x32_bf16(
                        a, bq[ks], st[ct], 0, 0, 0);
                }
            }
            float mloc = -INFINITY;
#pragma unroll
            for (int ct = 0; ct < 4; ct++)
#pragma unroll
                for (int reg = 0; reg < 4; reg++) {
                    int c_g = (ki << 6) + (ct << 4) + (quad << 2) + reg;
                    float s = st[ct][reg] * SCALE;
                    if (c_g > r_g) s = -INFINITY;
                    st[ct][reg] = s;
                    mloc = fmaxf(mloc, s);
                }
            mloc = fmaxf(mloc, __shfl_xor(mloc, 16));
            mloc = fmaxf(mloc, __shfl_xor(mloc, 32));
            float mnew = fmaxf(m_run, mloc);
            float corr = __expf(m_run - mnew);
            m_run = mnew;
            float rsum = 0.f;
#pragma unroll
            for (int ct = 0; ct < 4; ct++) {
                u16 pk[4];
#pragma unroll
                for (int reg = 0; reg < 4; reg++) {
                    float pv = __expf(st[ct][reg] - mnew);
                    rsum += pv;
                    pk[reg] = f2bf(pv);
                }
                uint2 pkv;
                pkv.x = (unsigned)pk[0] | ((unsigned)pk[1] << 16);
                pkv.y = (unsigned)pk[2] | ((unsigned)pk[3] << 16);
                *(uint2*)&Pa[(wave << 4) + l15][(ct << 4) + (quad << 2)] = pkv;
            }
            rsum += __shfl_xor(rsum, 16);
            rsum += __shfl_xor(rsum, 32);
            l_run = l_run * corr + rsum;
            float co[4];
#pragma unroll
            for (int reg = 0; reg < 4; reg++)
                co[reg] = __shfl(corr, ((lane >> 4) << 2) + reg);
#pragma unroll
            for (int dt = 0; dt < 4; dt++)
#pragma unroll
                for (int reg = 0; reg < 4; reg++) O[dt][reg] *= co[reg];
            __builtin_amdgcn_wave_barrier();
#pragma unroll
            for (int ks = 0; ks < 2; ks++) {
                short8 ap = *(const short8*)
                    &Pa[(wave << 4) + l15][(ks << 5) + (quad << 3)];
#pragma unroll
                for (int dt = 0; dt < 4; dt++) {
                    short8 bv = *(const short8*)
                        &Vt[(dt << 4) + l15][(ks << 5) + (quad << 3)];
                    O[dt] = __builtin_amdgcn_mfma_f32_16x16x32_bf16(
                        ap, bv, O[dt], 0, 0, 0);
                }
            }
        }
        float* ob = Op + (((size_t)bh * 32 + job) << 12);
#pragma unroll
        for (int dt = 0; dt < 4; dt++)
#pragma unroll
            for (int reg = 0; reg < 4; reg++) {
                int r = (wave << 4) + (quad << 2) + reg;
                int d = (dt << 4) + l15;
                ob[(r << 6) + d] = O[dt][reg];
            }
        if (quad == 0) {
            int r = (wave << 4) + l15;
            float* mlb = ml + (((size_t)bh * 32 + job) << 7);
            mlb[r] = m_run;
            mlb[64 + r] = l_run;
        }
    } else {
        // ----- k2a: chunk KV state (fp32 VALU, unchanged numerics) -----
        const int chunk = (int)blockIdx.x - 32;
        const int t0 = chunk << 6;
        float* Ksf = (float*)smem;            // [64][65]
        float* Vsf = Ksf + 64 * 65;           // [64][65]
        const u16* kp = kbp + (size_t)bh * T_ * D_;
        const u16* vp = vbp + (size_t)bh * T_ * D_;
#pragma unroll
        for (int ii = 0; ii < 16; ii++) {
            int idx = tid + (ii << 8);
            int row = idx >> 6, col = idx & 63;
            Ksf[row * 65 + col] =
                elu1(bf2f(kp[(size_t)(t0 + row) * D_ + col]) * SCALE);
            Vsf[row * 65 + col] = bf2f(vp[(size_t)(t0 + row) * D_ + col]);
        }
        __syncthreads();
        const int tr = tid >> 4, tc = tid & 15;
        const int d0 = tr * 4, e0 = tc * 4;
        float acc[4][4] = {};
        for (int c = 0; c < 64; c++) {
            float a[4], b[4];
#pragma unroll
            for (int i = 0; i < 4; i++) a[i] = Ksf[c * 65 + d0 + i];
#pragma unroll
            for (int j = 0; j < 4; j++) b[j] = Vsf[c * 65 + e0 + j];
#pragma unroll
            for (int i = 0; i < 4; i++)
#pragma unroll
                for (int j = 0; j < 4; j++) acc[i][j] += a[i] * b[j];
        }
        float* so = Sg + ((size_t)bh * 16 + chunk) * 4096;
#pragma unroll
        for (int i = 0; i < 4; i++) {
            float4 o = {acc[i][0], acc[i][1], acc[i][2], acc[i][3]};
            *reinterpret_cast<float4*>(&so[(d0 + i) * 64 + e0]) = o;
        }
        if (tc == 0) {
#pragma unroll
            for (int i = 0; i < 4; i++) {
                float s = 0.f;
                for (int c = 0; c < 64; c++) s += Ksf[c * 65 + d0 + i];
                svg[((size_t)bh * 16 + chunk) * 64 + d0 + i] = s;
            }
        }
    }
}

// ---------------------------------------------------------------------------
// K2s: in-place exclusive prefix scan over the chunk dim of Sg (and svg).
// ---------------------------------------------------------------------------
__global__ __launch_bounds__(256) void k2s_scan(
    float* __restrict__ Sg, float* __restrict__ svg)
{
    int gid = blockIdx.x * 256 + threadIdx.x;
    if (gid < 131072) {
        int bh = gid >> 12, e = gid & 4095;
        float* base = Sg + ((size_t)bh << 16) + e;
        float v[16];
#pragma unroll
        for (int c = 0; c < 16; c++) v[c] = base[(size_t)c << 12];
        float run = 0.f;
#pragma unroll
        for (int c = 0; c < 16; c++) {
            base[(size_t)c << 12] = run;
            run += v[c];
        }
    } else if (gid < 131072 + 2048) {
        int g2 = gid - 131072;
        int bh = g2 >> 6, d = g2 & 63;
        float* base = svg + ((size_t)bh << 10) + d;
        float v[16];
#pragma unroll
        for (int c = 0; c < 16; c++) v[c] = base[c << 6];
        float run = 0.f;
#pragma unroll
        for (int c = 0; c < 16; c++) {
            base[c << 6] = run;
            run += v[c];
        }
    }
}

// ---------------------------------------------------------------------------
// K2b: linear attention per chunk (fp32 VALU); prefix state float4 load.
// ---------------------------------------------------------------------------
__global__ __launch_bounds__(256) void k2b_lin(
    const u16* __restrict__ qbp, const u16* __restrict__ kbp,
    const u16* __restrict__ vbp,
    const float* __restrict__ Sg, const float* __restrict__ svg,
    const float* __restrict__ ang, const float* __restrict__ anb,
    float* __restrict__ ylin)
{
    const int chunk = blockIdx.x, bh = blockIdx.y;
    const int t0 = chunk << 6;
    __shared__ __align__(16) float bufA[64][68];
    __shared__ float bufQ[64][65];
    __shared__ float bufK[64][65];
    __shared__ float svec[64];
    const int tid = threadIdx.x;
    const u16* qp = qbp + (size_t)bh * T_ * D_;
    const u16* kp = kbp + (size_t)bh * T_ * D_;
    const u16* vp = vbp + (size_t)bh * T_ * D_;
    const float* sp = Sg + (((size_t)bh * 16 + chunk) << 12);
#pragma unroll
    for (int u = 0; u < 4; u++) {
        int idx = (tid + (u << 8)) << 2;
        int dd = idx >> 6, e = idx & 63;
        *(float4*)&bufA[dd][e] = *(const float4*)&sp[idx];
    }
    if (tid < 64) svec[tid] = svg[(((size_t)bh * 16 + chunk) << 6) + tid];
#pragma unroll
    for (int ii = 0; ii < 16; ii++) {
        int idx = tid + (ii << 8);
        int row = idx >> 6, col = idx & 63;
        bufQ[col][row] = elu1(bf2f(qp[(size_t)(t0 + row) * D_ + col]) * SCALE);
    }
    __syncthreads();
    const int tr = tid >> 4, tc = tid & 15;
    const int r0 = tr * 4, c0 = tc * 4;
    float N[4][4] = {};
    float pden[4];
    for (int dd = 0; dd < 64; dd++) {
        float a[4], b[4];
#pragma unroll
        for (int i = 0; i < 4; i++) a[i] = bufQ[dd][r0 + i];
#pragma unroll
        for (int j = 0; j < 4; j++) b[j] = bufA[dd][c0 + j];
#pragma unroll
        for (int i = 0; i < 4; i++)
#pragma unroll
            for (int j = 0; j < 4; j++) N[i][j] += a[i] * b[j];
    }
#pragma unroll
    for (int i = 0; i < 4; i++) {
        float s = 0.f;
#pragma unroll
        for (int j = 0; j < 4; j++) s += bufQ[c0 + j][r0 + i] * svec[c0 + j];
        pden[i] = s;
    }
    __syncthreads();
#pragma unroll
    for (int ii = 0; ii < 16; ii++) {
        int idx = tid + (ii << 8);
        int row = idx >> 6, col = idx & 63;
        bufK[col][row] = elu1(bf2f(kp[(size_t)(t0 + row) * D_ + col]) * SCALE);
        bufA[row][col] = bf2f(vp[(size_t)(t0 + row) * D_ + col]);
    }
    __syncthreads();
    float sc[4][4] = {};
    for (int dd = 0; dd < 64; dd++) {
        float a[4], b[4];
#pragma unroll
        for (int i = 0; i < 4; i++) a[i] = bufQ[dd][r0 + i];
#pragma unroll
        for (int j = 0; j < 4; j++) b[j] = bufK[dd][c0 + j];
#pragma unroll
        for (int i = 0; i < 4; i++)
#pragma unroll
            for (int j = 0; j < 4; j++) sc[i][j] += a[i] * b[j];
    }
    __syncthreads();
#pragma unroll
    for (int i = 0; i < 4; i++) {
        float s = 0.f;
#pragma unroll
        for (int j = 0; j < 4; j++) {
            float pv = ((c0 + j) <= (r0 + i)) ? sc[i][j] : 0.f;
            bufQ[c0 + j][r0 + i] = pv;
            s += pv;
        }
        pden[i] += s;
    }
#pragma unroll
    for (int i = 0; i < 4; i++) {
#pragma unroll
        for (int off = 1; off < 16; off <<= 1)
            pden[i] += __shfl_xor(pden[i], off);
    }
    __syncthreads();
    for (int c = 0; c < 64; c++) {
        float a[4], b[4];
#pragma unroll
        for (int i = 0; i < 4; i++) a[i] = bufQ[c][r0 + i];
#pragma unroll
        for (int j = 0; j < 4; j++) b[j] = bufA[c][c0 + j];
#pragma unroll
        for (int i = 0; i < 4; i++)
#pragma unroll
            for (int j = 0; j < 4; j++) N[i][j] += a[i] * b[j];
    }
    float yv[4][4], s1[4], s2[4];
#pragma unroll
    for (int i = 0; i < 4; i++) {
        float inv = 1.f / (pden[i] + 1e-4f);
        s1[i] = 0.f; s2[i] = 0.f;
#pragma unroll
        for (int j = 0; j < 4; j++) {
            float t = N[i][j] * inv;
            yv[i][j] = t; s1[i] += t; s2[i] += t * t;
        }
    }
#pragma unroll
    for (int i = 0; i < 4; i++) {
#pragma unroll
        for (int off = 1; off < 16; off <<= 1) {
            s1[i] += __shfl_xor(s1[i], off);
            s2[i] += __shfl_xor(s2[i], off);
        }
    }
#pragma unroll
    for (int i = 0; i < 4; i++) {
        float mean = s1[i] * (1.f / 64.f);
        float var = s2[i] * (1.f / 64.f) - mean * mean;
        float rstd = rsqrtf(var + 1e-5f);
        float4 o;
        o.x = (yv[i][0] - mean) * rstd * ang[c0 + 0] + anb[c0 + 0];
        o.y = (yv[i][1] - mean) * rstd * ang[c0 + 1] + anb[c0 + 1];
        o.z = (yv[i][2] - mean) * rstd * ang[c0 + 2] + anb[c0 + 2];
        o.w = (yv[i][3] - mean) * rstd * ang[c0 + 3] + anb[c0 + 3];
        *reinterpret_cast<float4*>(
            &ylin[((size_t)bh * T_ + t0 + r0 + i) * D_ + c0]) = o;
    }
}

// ---------------------------------------------------------------------------
// K4: fused split-K combine + alpha-blend + out-LN + pre-LN + block-diag mix
// (reversed) + folded bilinear + bias.  One block per token.
// ---------------------------------------------------------------------------
__global__ __launch_bounds__(256) void k4_proj(
    const float* __restrict__ Op, const float* __restrict__ ml,
    const float* __restrict__ ylin, const float* __restrict__ fg,
    const float* __restrict__ og, const float* __restrict__ ob,
    const float* __restrict__ pg, const float* __restrict__ pb,
    const float* __restrict__ bw, const float* __restrict__ Mg,
    const float* __restrict__ pbias, float* __restrict__ out)
{
    const int tok = blockIdx.x;
    const int bi = tok >> 10, t = tok & 1023;
    const int qi = t >> 6, r = t & 63;
    __shared__ float ybuf[1024];
    __shared__ float xb[1024];
    __shared__ float red[8];
    const int tid = threadIdx.x;
    {
        const float al = 1.f / (1.f + __expf(-fg[0]));
        const int h = tid >> 4;
        const int d4 = (tid & 15) << 2;
        const int bh = (bi << 4) + h;
        const size_t b0 = (((size_t)bh * 32 + (qi << 1)) << 7);
        float m0 = ml[b0 + r], l0 = ml[b0 + 64 + r];
        float m1 = ml[b0 + 128 + r], l1 = ml[b0 + 192 + r];
        float m = fmaxf(m0, m1);
        float w0 = (m0 == -INFINITY) ? 0.f : __expf(m0 - m);
        float w1 = __expf(m1 - m);
        float inv = al / (l0 * w0 + l1 * w1);
        const float* o0 = Op + (((size_t)bh * 32 + (qi << 1)) << 12) + (r << 6);
        const float* o1 = o0 + 4096;
        float4 a = *(const float4*)&o0[d4];
        float4 b = *(const float4*)&o1[d4];
        float4 yl = *(const float4*)
            &ylin[((((size_t)bh << 10) + t) << 6) + d4];
        float4 o;
        o.x = (a.x * w0 + b.x * w1) * inv + (1.f - al) * yl.x;
        o.y = (a.y * w0 + b.y * w1) * inv + (1.f - al) * yl.y;
        o.z = (a.z * w0 + b.z * w1) * inv + (1.f - al) * yl.z;
        o.w = (a.w * w0 + b.w * w1) * inv + (1.f - al) * yl.w;
        *(float4*)&ybuf[(h << 6) + d4] = o;
    }
    __syncthreads();
    const int c0 = tid << 2;
    float4 v4 = *reinterpret_cast<const float4*>(&ybuf[c0]);
    float v[4] = {v4.x, v4.y, v4.z, v4.w};
    float s1 = v[0] + v[1] + v[2] + v[3];
    float s2 = v[0]*v[0] + v[1]*v[1] + v[2]*v[2] + v[3]*v[3];
#pragma unroll
    for (int off = 1; off < 64; off <<= 1) {
        s1 += __shfl_xor(s1, off); s2 += __shfl_xor(s2, off);
    }
    if ((tid & 63) == 0) { red[(tid >> 6) * 2] = s1; red[(tid >> 6) * 2 + 1] = s2; }
    __syncthreads();
    s1 = red[0] + red[2] + red[4] + red[6];
    s2 = red[1] + red[3] + red[5] + red[7];
    __syncthreads();
    {
        float mean = s1 * (1.f / 1024.f);
        float var = s2 * (1.f / 1024.f) - mean * mean;
        float rstd = rsqrtf(var + 1e-5f);
#pragma unroll
        for (int q = 0; q < 4; q++)
            v[q] = (v[q] - mean) * rstd * og[c0 + q] + ob[c0 + q];
    }
    s1 = v[0] + v[1] + v[2] + v[3];
    s2 = v[0]*v[0] + v[1]*v[1] + v[2]*v[2] + v[3]*v[3];
#pragma unroll
    for (int off = 1; off < 64; off <<= 1) {
        s1 += __shfl_xor(s1, off); s2 += __shfl_xor(s2, off);
    }
    if ((tid & 63) == 0) { red[(tid >> 6) * 2] = s1; red[(tid >> 6) * 2 + 1] = s2; }
    __syncthreads();
    s1 = red[0] + red[2] + red[4] + red[6];
    s2 = red[1] + red[3] + red[5] + red[7];
    {
        float mean = s1 * (1.f / 1024.f);
        float var = s2 * (1.f / 1024.f) - mean * mean;
        float rstd = rsqrtf(var + 1e-5f);
#pragma unroll
        for (int q = 0; q < 4; q++)
            xb[c0 + q] = (v[q] - mean) * rstd * pg[c0 + q] + pb[c0 + q];
    }
    __syncthreads();
    const int g = tid >> 2;
    const int jb = (tid & 3) << 2;
    float acc[4] = {0.f, 0.f, 0.f, 0.f};
    {
        const float* xg = &xb[g << 4];
        const float* bwg = &bw[(g << 8) + jb];
        for (int i = 0; i < 16; i++) {
            float xv = xg[i];
            float4 wv = *reinterpret_cast<const float4*>(&bwg[i << 4]);
            acc[0] += xv * wv.x; acc[1] += xv * wv.y;
            acc[2] += xv * wv.z; acc[3] += xv * wv.w;
        }
    }
    const int C0 = ((63 - g) << 4) + 12 - jb;
    const int i2 = C0 >> 5, r0 = C0 & 31;
    float z2[4] = {0.f, 0.f, 0.f, 0.f};
    {
        const float* xg = &xb[i2 << 5];
        const float* mg = &Mg[r0];
        for (int j = 0; j < 32; j++) {
            float xv = xg[j];
            float4 mv = *reinterpret_cast<const float4*>(&mg[j << 5]);
            z2[0] += xv * mv.x; z2[1] += xv * mv.y;
            z2[2] += xv * mv.z; z2[3] += xv * mv.w;
        }
    }
    float4 bz = *reinterpret_cast<const float4*>(&pbias[C0]);
    float4 o;
    o.x = acc[3] + z2[0] + bz.x;
    o.y = acc[2] + z2[1] + bz.y;
    o.z = acc[1] + z2[2] + bz.z;
    o.w = acc[0] + z2[3] + bz.w;
    *reinterpret_cast<float4*>(&out[((size_t)tok << 10) + C0]) = o;
}

// ---------------------------------------------------------------------------
extern "C" void kernel_launch(void* const* d_in, const int* in_sizes, int n_in,
                              void* d_out, int out_size, void* d_ws, size_t ws_size,
                              hipStream_t stream) {
    const float* x   = (const float*)d_in[0];
    const float* w   = (const float*)d_in[1];
    const float* wb  = (const float*)d_in[2];
    const float* fg  = (const float*)d_in[3];
    const float* ang = (const float*)d_in[4];
    const float* anb = (const float*)d_in[5];
    const float* ong = (const float*)d_in[6];
    const float* onb = (const float*)d_in[7];
    const float* ppg = (const float*)d_in[8];
    const float* ppb = (const float*)d_in[9];
    const float* pbw = (const float*)d_in[10];
    const float* pwr = (const float*)d_in[11];
    const float* pwc = (const float*)d_in[12];
    const float* pal = (const float*)d_in[13];
    const float* pbi = (const float*)d_in[14];

    uint8_t* p = (uint8_t*)d_ws;
    u16* xbf = (u16*)p;  p += (size_t)2048 * 1024 * 2;
    u16* wbf = (u16*)p;  p += (size_t)3072 * 1024 * 2;
    u16* qb  = (u16*)p;  p += (size_t)32 * 1024 * 64 * 2;
    u16* kb  = (u16*)p;  p += (size_t)32 * 1024 * 64 * 2;
    u16* vb  = (u16*)p;  p += (size_t)32 * 1024 * 64 * 2;
    u16* vtb = (u16*)p;  p += (size_t)32 * 1024 * 64 * 2;
    float* ylin  = (float*)p;  p += (size_t)32 * 1024 * 64 * 4;
    float* Sg    = (float*)p;  p += (size_t)32 * 16 * 4096 * 4;
    float* svg   = (float*)p;  p += (size_t)32 * 16 * 64 * 4;
    float* Mg    = (float*)p;  p += (size_t)32 * 32 * 4;
    float* Op    = (float*)p;  p += (size_t)32 * 32 * 4096 * 4;
    float* ml    = (float*)p;  p += (size_t)32 * 32 * 128 * 4;
    float* out   = (float*)d_out;

    k0_prep<<<5121, 256, 0, stream>>>(x, w, pwc, pwr, pal, xbf, wbf, Mg);
    k1_qkv<<<dim3(24, 16), 256, 0, stream>>>(xbf, wbf, wb, qb, kb, vb, vtb);
    k23<<<dim3(48, 32), 256, 0, stream>>>(qb, kb, vb, vtb, Sg, svg, Op, ml);
    k2s_scan<<<521, 256, 0, stream>>>(Sg, svg);
    k2b_lin<<<dim3(16, 32), 256, 0, stream>>>(qb, kb, vb, Sg, svg, ang, anb, ylin);
    k4_proj<<<2048, 256, 0, stream>>>(Op, ml, ylin, fg, ong, onb, ppg, ppb,
                                      pbw, Mg, pbi, out);
}